// Round 1
// baseline (550.055 us; speedup 1.0000x reference)
//
#include <hip/hip_runtime.h>

// SNN fused kernel, MI355X (gfx950).
// Reference: conv1d(50-tap gaussian, SAME) -> *2 -> >0.5 spikes ->
// cur1 = spk @ W1^T -> 25-step LIF (beta=0.95, thr=1, reset-by-sub) ->
// spk_rec [25,B,5] f32, plus spike_count = spikes.sum()*25.
//
// Layout: thread = one row. Rolling 64-register conv window (15 outputs /
// stage, 13 stages covers L=187). filt[k] / W1T[l*50+h] / W2[c*50+h] are
// wave-uniform addresses -> scalar (SMEM) loads, co-issue with VALU.
// Spike count: per-lane int -> wave shfl reduce -> u32 atomic (deterministic).

constexpr int L   = 187;
constexpr int KF  = 50;
constexpr int H   = 50;
constexpr int C   = 5;
constexpr int NST = 25;
constexpr float BETA = 0.95f;
// spike condition: y*2 > 0.5  <=>  y > 0.25
constexpr float YTH = 0.25f;

__global__ void __launch_bounds__(256) transpose_w1(
    const float* __restrict__ W1, float* __restrict__ W1T)
{
    int i = blockIdx.x * 256 + threadIdx.x;   // i = h*L + l
    if (i < H * L) {
        int h = i / L, l = i - h * L;
        W1T[l * H + h] = W1[i];
    }
}

template<bool TR>
__global__ void __launch_bounds__(256) snn_fused(
    const float* __restrict__ x,   const float* __restrict__ filt,
    const float* __restrict__ W1,  const float* __restrict__ W1T,
    const float* __restrict__ W2,  float* __restrict__ out,
    unsigned int* __restrict__ cnt_ws, int B)
{
    const int row   = blockIdx.x * 256 + threadIdx.x;
    const bool valid = row < B;
    const int r     = valid ? row : (B - 1);        // clamp: safe loads
    const float* __restrict__ xr = x + (size_t)r * L;

    // ---------------- encoder conv + cur1 ----------------
    float w[64];            // window holds xpad[15*s + i], i in [0,64)
    float cur1[H];
    #pragma unroll
    for (int h = 0; h < H; ++h) cur1[h] = 0.f;
    int cnt = 0;

    // init: xpad[p] = (24 <= p < 211) ? x[p-24] : 0
    #pragma unroll
    for (int i = 0; i < 64; ++i) w[i] = (i >= 24) ? xr[i - 24] : 0.f;

    #pragma unroll 1
    for (int s = 0; s < 12; ++s) {                  // l = 15s+j <= 179 < 187
        const int l0 = s * 15;
        #pragma unroll
        for (int j = 0; j < 15; ++j) {
            const int l = l0 + j;
            float y = 0.f;
            #pragma unroll
            for (int k = 0; k < KF; ++k) y = fmaf(w[j + k], filt[k], y);
            const bool  sb = y > YTH;
            const float sp = sb ? 1.0f : 0.0f;
            cnt += sb;
            #pragma unroll
            for (int h = 0; h < H; ++h) {
                const float wv = TR ? W1T[l * H + h] : W1[h * L + l];
                cur1[h] = fmaf(sp, wv, cur1[h]);
            }
        }
        // shift window by 15, refill tail: new w[i] = xpad[15(s+1)+i]
        #pragma unroll
        for (int i = 0; i < 49; ++i) w[i] = w[i + 15];
        #pragma unroll
        for (int d = 0; d < 15; ++d) {
            const int g = l0 + 40 + d;              // = 15(s+1)+49+d-24
            float v = 0.f;
            if (g < L) v = xr[g];
            w[49 + d] = v;
        }
    }
    {   // peeled stage s = 12: l = 180..186
        #pragma unroll
        for (int j = 0; j < 7; ++j) {
            const int l = 180 + j;
            float y = 0.f;
            #pragma unroll
            for (int k = 0; k < KF; ++k) y = fmaf(w[j + k], filt[k], y);
            const bool  sb = y > YTH;
            const float sp = sb ? 1.0f : 0.0f;
            cnt += sb;
            #pragma unroll
            for (int h = 0; h < H; ++h) {
                const float wv = TR ? W1T[l * H + h] : W1[h * L + l];
                cur1[h] = fmaf(sp, wv, cur1[h]);
            }
        }
    }

    // ---------------- spike count: wave reduce + one atomic ----------------
    int wc = valid ? cnt : 0;
    #pragma unroll
    for (int off = 32; off > 0; off >>= 1) wc += __shfl_down(wc, off);
    if ((threadIdx.x & 63) == 0) atomicAdd(cnt_ws, (unsigned int)wc);

    // ---------------- LIF dynamics, 25 steps ----------------
    float m1[H], m2[C];
    #pragma unroll
    for (int h = 0; h < H; ++h) m1[h] = 0.f;
    #pragma unroll
    for (int c = 0; c < C; ++c) m2[c] = 0.f;

    float* __restrict__ orow = out + (size_t)r * C;
    const size_t ostep = (size_t)B * C;

    #pragma unroll 1
    for (int t = 0; t < NST; ++t) {
        float cur2[C];
        #pragma unroll
        for (int c = 0; c < C; ++c) cur2[c] = 0.f;
        #pragma unroll
        for (int h = 0; h < H; ++h) {
            float m = fmaf(BETA, m1[h], cur1[h]);
            const float sp = (m > 1.0f) ? 1.0f : 0.0f;
            m1[h] = m - sp;                          // reset by subtraction
            #pragma unroll
            for (int c = 0; c < C; ++c)
                cur2[c] = fmaf(sp, W2[c * H + h], cur2[c]);
        }
        float* __restrict__ ot = orow + (size_t)t * ostep;
        #pragma unroll
        for (int c = 0; c < C; ++c) {
            float m = fmaf(BETA, m2[c], cur2[c]);
            const float s2 = (m > 1.0f) ? 1.0f : 0.0f;
            m2[c] = m - s2;
            if (valid) ot[c] = s2;
        }
    }
}

__global__ void finalize_count(const unsigned int* __restrict__ cnt,
                               float* __restrict__ out, size_t off)
{
    if (threadIdx.x == 0 && blockIdx.x == 0)
        out[off] = (float)((double)(*cnt) * 25.0);
}

extern "C" void kernel_launch(void* const* d_in, const int* in_sizes, int n_in,
                              void* d_out, int out_size, void* d_ws, size_t ws_size,
                              hipStream_t stream)
{
    const float* x    = (const float*)d_in[0];
    const float* filt = (const float*)d_in[1];
    const float* W1   = (const float*)d_in[2];
    const float* W2   = (const float*)d_in[3];
    float* out        = (float*)d_out;
    const int B       = in_sizes[0] / L;            // 131072

    unsigned int* cnt_ws = (unsigned int*)d_ws;
    float* W1T = (float*)((char*)d_ws + 64);
    const size_t need = 64 + sizeof(float) * (size_t)L * H;

    hipMemsetAsync(cnt_ws, 0, sizeof(unsigned int), stream);

    const int grid = (B + 255) / 256;
    if (ws_size >= need) {
        transpose_w1<<<(H * L + 255) / 256, 256, 0, stream>>>(W1, W1T);
        snn_fused<true><<<grid, 256, 0, stream>>>(x, filt, W1, W1T, W2, out, cnt_ws, B);
    } else {
        snn_fused<false><<<grid, 256, 0, stream>>>(x, filt, W1, W1T, W2, out, cnt_ws, B);
    }
    finalize_count<<<1, 1, 0, stream>>>(cnt_ws, out, (size_t)NST * B * C);
}

// Round 2
// 148.837 us; speedup vs baseline: 3.6957x; 3.6957x over previous
//
#include <hip/hip_runtime.h>

// Fused SNN, MFMA-based. MI355X (gfx950).
// Stage A (per 16-row tile, per wave): Y = X @ Toeplitz(filt) via
//   mfma_f32_16x16x32_bf16 (band k-tiles), threshold -> spikes (count) ->
//   spikes repacked bf16 in per-wave LDS -> cur1 = S @ W1^T via MFMA.
// Stage B: cur1 repacked to per-wave LDS f32, LIF 25 steps with 2 lanes/row
//   (h split 28/28, shfl_xor reduce of cur2), W2 broadcast from LDS.

typedef float  f32x4 __attribute__((ext_vector_type(4)));
typedef short  s16x8 __attribute__((ext_vector_type(8)));

constexpr int L  = 187;
constexpr int H  = 50;
constexpr int C  = 5;
constexpr int NST = 25;
constexpr int KP = 192;          // padded conv K/N
constexpr float BETA = 0.95f;
constexpr float YTH  = 0.25f;    // y*2 > 0.5  <=>  y > 0.25

__device__ inline unsigned short f2bf(float f) {
    union { float f; unsigned u; } v; v.f = f;
    unsigned r = (v.u + 0x7FFFu + ((v.u >> 16) & 1u)) >> 16;   // RNE
    return (unsigned short)r;
}

// ---- prep: Tt[n][k] = f[k-n+24] (bf16, zero-padded), W1f[h][k] = W1[h][k] ----
__global__ void __launch_bounds__(256) prep_mats(
    const float* __restrict__ filt, const float* __restrict__ W1,
    unsigned short* __restrict__ Tt, unsigned short* __restrict__ W1f)
{
    int i = blockIdx.x * 256 + threadIdx.x;
    if (i < KP * KP) {
        int n = i / KP, k = i - n * KP;
        int d = k - n + 24;
        unsigned short v = 0;
        if (n < L && k < L && d >= 0 && d < 50) v = f2bf(filt[d]);
        Tt[i] = v;
    } else {
        int i2 = i - KP * KP;
        if (i2 < 64 * KP) {
            int h = i2 / KP, k = i2 - h * KP;
            unsigned short v = 0;
            if (h < H && k < L) v = f2bf(W1[h * L + k]);
            W1f[i2] = v;
        }
    }
}

__global__ void __launch_bounds__(256) snn_main(
    const float* __restrict__ x, const unsigned short* __restrict__ Tt,
    const unsigned short* __restrict__ W1f, const float* __restrict__ W2,
    float* __restrict__ out, unsigned int* __restrict__ cnt, int B)
{
    __shared__ unsigned short Sl[4][32][200];   // per-wave spike tile / cur1 overlay
    __shared__ float W2L[64][8];                // W2 transposed [h][c], zero-padded

    const int tid = threadIdx.x;
    for (int i = tid; i < 64 * 8; i += 256) {
        int h = i >> 3, c = i & 7;
        W2L[h][c] = (h < H && c < C) ? W2[c * H + h] : 0.f;
    }
    __syncthreads();

    const int wid  = tid >> 6, lane = tid & 63;
    const int lm   = lane & 15, lk = lane >> 4;
    const int rowbase = blockIdx.x * 128 + wid * 32;

    // ---------- A fragments: 2 m-tiles x 6 k-tiles, bf16 ----------
    s16x8 a1[2][6];
    #pragma unroll
    for (int mt = 0; mt < 2; ++mt) {
        const float* __restrict__ xr = x + (size_t)(rowbase + mt * 16 + lm) * L;
        #pragma unroll
        for (int kt = 0; kt < 6; ++kt) {
            s16x8 v;
            #pragma unroll
            for (int j = 0; j < 8; ++j) {
                int k = kt * 32 + lk * 8 + j;
                float f = (k < L) ? xr[k] : 0.f;
                v[j] = (short)f2bf(f);
            }
            a1[mt][kt] = v;
        }
    }

    // ---------- GEMM1: conv, threshold, spike count ----------
    int scnt = 0;
    #pragma unroll
    for (int nt = 0; nt < 12; ++nt) {
        constexpr int lo[12] = {0,0,0,0,1,1,2,2,3,3,4,4};
        constexpr int hi[12] = {1,1,2,2,3,3,4,4,5,5,5,5};
        f32x4 acc0 = {0,0,0,0}, acc1 = {0,0,0,0};
        #pragma unroll
        for (int kt = 0; kt < 6; ++kt) {
            if (kt >= lo[nt] && kt <= hi[nt]) {
                s16x8 b = *(const s16x8*)(Tt + (nt * 16 + lm) * KP + kt * 32 + lk * 8);
                acc0 = __builtin_amdgcn_mfma_f32_16x16x32_bf16(a1[0][kt], b, acc0, 0, 0, 0);
                acc1 = __builtin_amdgcn_mfma_f32_16x16x32_bf16(a1[1][kt], b, acc1, 0, 0, 0);
            }
        }
        #pragma unroll
        for (int j = 0; j < 4; ++j) {     // D: row = 4*lk+j, col = lm
            bool s0 = acc0[j] > YTH, s1 = acc1[j] > YTH;
            scnt += (int)s0 + (int)s1;
            Sl[wid][     4 * lk + j][nt * 16 + lm] = s0 ? 0x3F80 : 0;
            Sl[wid][16 + 4 * lk + j][nt * 16 + lm] = s1 ? 0x3F80 : 0;
        }
    }

    #pragma unroll
    for (int off = 32; off; off >>= 1) scnt += __shfl_down(scnt, off);
    if (lane == 0) atomicAdd(cnt, (unsigned)scnt);

    // ---------- GEMM2: cur1 = spikes @ W1^T ----------
    f32x4 c0[4], c1[4];
    #pragma unroll
    for (int n2 = 0; n2 < 4; ++n2) { c0[n2] = (f32x4){0,0,0,0}; c1[n2] = (f32x4){0,0,0,0}; }
    #pragma unroll
    for (int kt = 0; kt < 6; ++kt) {
        s16x8 a20 = *(const s16x8*)&Sl[wid][lm     ][kt * 32 + lk * 8];
        s16x8 a21 = *(const s16x8*)&Sl[wid][16 + lm][kt * 32 + lk * 8];
        #pragma unroll
        for (int n2 = 0; n2 < 4; ++n2) {
            s16x8 b2 = *(const s16x8*)(W1f + (n2 * 16 + lm) * KP + kt * 32 + lk * 8);
            c0[n2] = __builtin_amdgcn_mfma_f32_16x16x32_bf16(a20, b2, c0[n2], 0, 0, 0);
            c1[n2] = __builtin_amdgcn_mfma_f32_16x16x32_bf16(a21, b2, c1[n2], 0, 0, 0);
        }
    }

    // ---------- repack cur1 into per-wave LDS f32 [32][68] (overlay on Sl) ----------
    asm volatile("s_waitcnt lgkmcnt(0)" ::: "memory");
    float* Cl = (float*)&Sl[wid][0][0];
    #pragma unroll
    for (int n2 = 0; n2 < 4; ++n2)
        #pragma unroll
        for (int j = 0; j < 4; ++j) {
            Cl[(     4 * lk + j) * 68 + n2 * 16 + lm] = c0[n2][j];
            Cl[(16 + 4 * lk + j) * 68 + n2 * 16 + lm] = c1[n2][j];
        }
    asm volatile("s_waitcnt lgkmcnt(0)" ::: "memory");

    // ---------- LIF: 2 lanes per row, h split 28/28 ----------
    const int r = lane >> 1, half = lane & 1;
    const int hbase = half * 28;                 // h in [0,28) or [28,56); >=50 are zeros
    float cu[28], m1[28];
    #pragma unroll
    for (int i = 0; i < 7; ++i) {
        f32x4 v = *(const f32x4*)&Cl[r * 68 + hbase + 4 * i];
        cu[4*i] = v[0]; cu[4*i+1] = v[1]; cu[4*i+2] = v[2]; cu[4*i+3] = v[3];
    }
    #pragma unroll
    for (int i = 0; i < 28; ++i) m1[i] = 0.f;
    float m2[5] = {0, 0, 0, 0, 0};
    const size_t row = (size_t)rowbase + r;

    #pragma unroll 1
    for (int t = 0; t < NST; ++t) {
        asm volatile("" ::: "memory");           // block LICM of 140 W2L loads
        float c2[5] = {0, 0, 0, 0, 0};
        #pragma unroll
        for (int i = 0; i < 28; ++i) {
            float m = fmaf(BETA, m1[i], cu[i]);
            bool s = m > 1.f;
            m1[i] = s ? m - 1.f : m;
            float spk = s ? 1.f : 0.f;
            const int h = hbase + i;
            f32x4 w4 = *(const f32x4*)&W2L[h][0];
            float w5 = W2L[h][4];
            c2[0] = fmaf(spk, w4[0], c2[0]);
            c2[1] = fmaf(spk, w4[1], c2[1]);
            c2[2] = fmaf(spk, w4[2], c2[2]);
            c2[3] = fmaf(spk, w4[3], c2[3]);
            c2[4] = fmaf(spk, w5,    c2[4]);
        }
        #pragma unroll
        for (int c = 0; c < 5; ++c) c2[c] += __shfl_xor(c2[c], 1);
        float* __restrict__ ot = out + ((size_t)t * B + row) * 5;
        #pragma unroll
        for (int c = 0; c < 5; ++c) {
            float m = fmaf(BETA, m2[c], c2[c]);
            bool s2 = m > 1.f;
            m2[c] = s2 ? m - 1.f : m;
            float sv = s2 ? 1.f : 0.f;
            if (half == 0 ? (c < 3) : (c >= 3)) ot[c] = sv;
        }
    }
}

__global__ void finalize_count(const unsigned int* __restrict__ cnt,
                               float* __restrict__ out, size_t off)
{
    if (threadIdx.x == 0 && blockIdx.x == 0)
        out[off] = (float)((double)(*cnt) * 25.0);
}

// ================= fallback (round-1 kernel), used only if ws too small ======
__global__ void __launch_bounds__(256) snn_fallback(
    const float* __restrict__ x, const float* __restrict__ filt,
    const float* __restrict__ W1, const float* __restrict__ W2,
    float* __restrict__ out, unsigned int* __restrict__ cnt_ws, int B)
{
    const int row = blockIdx.x * 256 + threadIdx.x;
    const bool valid = row < B;
    const int rr = valid ? row : (B - 1);
    const float* __restrict__ xr = x + (size_t)rr * L;
    float w[64], cur1[H];
    #pragma unroll
    for (int h = 0; h < H; ++h) cur1[h] = 0.f;
    int cntv = 0;
    #pragma unroll
    for (int i = 0; i < 64; ++i) w[i] = (i >= 24) ? xr[i - 24] : 0.f;
    #pragma unroll 1
    for (int s = 0; s < 12; ++s) {
        const int l0 = s * 15;
        #pragma unroll
        for (int j = 0; j < 15; ++j) {
            const int l = l0 + j;
            float y = 0.f;
            #pragma unroll
            for (int k = 0; k < 50; ++k) y = fmaf(w[j + k], filt[k], y);
            const bool sb = y > YTH;
            cntv += sb;
            const float sp = sb ? 1.f : 0.f;
            #pragma unroll
            for (int h = 0; h < H; ++h) cur1[h] = fmaf(sp, W1[h * L + l], cur1[h]);
        }
        #pragma unroll
        for (int i = 0; i < 49; ++i) w[i] = w[i + 15];
        #pragma unroll
        for (int d = 0; d < 15; ++d) {
            const int g = l0 + 40 + d;
            w[49 + d] = (g < L) ? xr[g] : 0.f;
        }
    }
    #pragma unroll
    for (int j = 0; j < 7; ++j) {
        const int l = 180 + j;
        float y = 0.f;
        #pragma unroll
        for (int k = 0; k < 50; ++k) y = fmaf(w[j + k], filt[k], y);
        const bool sb = y > YTH;
        cntv += sb;
        const float sp = sb ? 1.f : 0.f;
        #pragma unroll
        for (int h = 0; h < H; ++h) cur1[h] = fmaf(sp, W1[h * L + l], cur1[h]);
    }
    int wc = valid ? cntv : 0;
    #pragma unroll
    for (int off = 32; off; off >>= 1) wc += __shfl_down(wc, off);
    if ((threadIdx.x & 63) == 0) atomicAdd(cnt_ws, (unsigned)wc);
    float m1[H], m2[C];
    #pragma unroll
    for (int h = 0; h < H; ++h) m1[h] = 0.f;
    #pragma unroll
    for (int c = 0; c < C; ++c) m2[c] = 0.f;
    #pragma unroll 1
    for (int t = 0; t < NST; ++t) {
        float c2[C] = {0, 0, 0, 0, 0};
        #pragma unroll
        for (int h = 0; h < H; ++h) {
            float m = fmaf(BETA, m1[h], cur1[h]);
            const float sp = (m > 1.f) ? 1.f : 0.f;
            m1[h] = m - sp;
            #pragma unroll
            for (int c = 0; c < C; ++c) c2[c] = fmaf(sp, W2[c * H + h], c2[c]);
        }
        float* __restrict__ ot = out + ((size_t)t * B + rr) * C;
        #pragma unroll
        for (int c = 0; c < C; ++c) {
            float m = fmaf(BETA, m2[c], c2[c]);
            const float s2 = (m > 1.f) ? 1.f : 0.f;
            m2[c] = m - s2;
            if (valid) ot[c] = s2;
        }
    }
}

extern "C" void kernel_launch(void* const* d_in, const int* in_sizes, int n_in,
                              void* d_out, int out_size, void* d_ws, size_t ws_size,
                              hipStream_t stream)
{
    const float* x    = (const float*)d_in[0];
    const float* filt = (const float*)d_in[1];
    const float* W1   = (const float*)d_in[2];
    const float* W2   = (const float*)d_in[3];
    float* out        = (float*)d_out;
    const int B       = in_sizes[0] / L;        // 131072

    unsigned int* cnt = (unsigned int*)d_ws;
    unsigned short* Tt  = (unsigned short*)((char*)d_ws + 64);
    unsigned short* W1f = (unsigned short*)((char*)d_ws + 64 + KP * KP * 2);
    const size_t need = 64 + (size_t)KP * KP * 2 + (size_t)64 * KP * 2;

    hipMemsetAsync(cnt, 0, sizeof(unsigned int), stream);

    if (ws_size >= need && (B % 128) == 0) {
        prep_mats<<<(KP * KP + 64 * KP + 255) / 256, 256, 0, stream>>>(filt, W1, Tt, W1f);
        snn_main<<<B / 128, 256, 0, stream>>>(x, Tt, W1f, W2, out, cnt, B);
    } else {
        snn_fallback<<<(B + 255) / 256, 256, 0, stream>>>(x, filt, W1, W2, out, cnt, B);
    }
    finalize_count<<<1, 1, 0, stream>>>(cnt, out, (size_t)NST * B * C);
}